// Round 1
// baseline (24098.647 us; speedup 1.0000x reference)
//
#include <hip/hip_runtime.h>

#define TSTEPS 365
#define NCELLS 65536
#define HID 64

// One thread per grid cell; entire 365-step recurrence in-kernel (cells are
// independent -> no grid sync needed). Weights are read with wave-uniform
// indices so the compiler emits scalar s_load + v_fmac with SGPR operand.
// h lives in VGPRs (compile-time indexed k-loop); the single runtime-indexed
// h[u] diagonal access goes through an LDS double buffer (column-private per
// thread -> no barriers, no bank conflicts: lanes hit consecutive banks).
__global__ __launch_bounds__(64, 1)
void gru_seq_kernel(const float* __restrict__ precip,
                    const float* __restrict__ temp,
                    const float* __restrict__ w_ih,    // (192,2)
                    const float* __restrict__ w_hh,    // (192,64)
                    const float* __restrict__ bias,    // (192)
                    const float* __restrict__ bias_n,  // (64)
                    const float* __restrict__ out_w,   // (64)
                    const float* __restrict__ out_b,   // (1)
                    const float* __restrict__ init_h,  // (64)
                    float* __restrict__ out)           // smb (365*65536) ++ final_h (65536*64)
{
    __shared__ float hbuf[2][HID][64];   // [buffer][unit][thread] = 32 KiB
    const int tid  = threadIdx.x;
    const int cell = blockIdx.x * 64 + tid;

    float h[HID];
#pragma unroll
    for (int u = 0; u < HID; ++u) {
        h[u] = init_h[u];                // uniform -> s_load broadcast
        hbuf[0][u][tid] = h[u];
    }
    const float ob = out_b[0];

    for (int t = 0; t < TSTEPS; ++t) {
        const int pb = t & 1;
        const float p  = precip[(size_t)t * NCELLS + cell];   // coalesced
        const float tm = temp  [(size_t)t * NCELLS + cell];   // coalesced
        float y = ob;

        for (int u = 0; u < HID; ++u) {   // u runtime-uniform -> scalar weight loads
            const float* wr = w_hh + u * HID;
            const float* wz = wr + 64 * HID;
            const float* wn = wz + 64 * HID;
            float hr = 0.f, hz = 0.f, hn = 0.f;
#pragma unroll
            for (int k = 0; k < HID; ++k) {
                hr = fmaf(wr[k], h[k], hr);
                hz = fmaf(wz[k], h[k], hz);
                hn = fmaf(wn[k], h[k], hn);
            }
            // igates = x @ W_ih^T + bias   (x = [precip, temp])
            const float ir  = fmaf(w_ih[2*u      ], p, fmaf(w_ih[2*u + 1  ], tm, bias[u      ]));
            const float iz  = fmaf(w_ih[2*u + 128], p, fmaf(w_ih[2*u + 129], tm, bias[u + 64 ]));
            const float in_ = fmaf(w_ih[2*u + 256], p, fmaf(w_ih[2*u + 257], tm, bias[u + 128]));

            const float r = 1.f / (1.f + __expf(-(ir + hr)));
            const float z = 1.f / (1.f + __expf(-(iz + hz)));
            float npre = in_ + r * (hn + bias_n[u]);
            npre = fminf(30.f, fmaxf(-30.f, npre));
            const float e2  = __expf(npre + npre);
            const float nnw = 1.f - 2.f / (e2 + 1.f);          // tanh(npre)

            const float hold = hbuf[pb][u][tid];               // runtime-indexed old h
            const float hx   = nnw + z * (hold - nnw);         // equinox GRU update
            hbuf[1 - pb][u][tid] = hx;
            y = fmaf(hx, out_w[u], y);
        }

#pragma unroll
        for (int u = 0; u < HID; ++u) h[u] = hbuf[1 - pb][u][tid];

        out[(size_t)t * NCELLS + cell] = y;                    // coalesced
    }

    // final_h: (H, W, 64) -> flat cell*64 + u
#pragma unroll
    for (int u = 0; u < HID; ++u)
        out[(size_t)TSTEPS * NCELLS + (size_t)cell * HID + u] = h[u];
}

extern "C" void kernel_launch(void* const* d_in, const int* in_sizes, int n_in,
                              void* d_out, int out_size, void* d_ws, size_t ws_size,
                              hipStream_t stream) {
    const float* precip = (const float*)d_in[0];
    const float* temp   = (const float*)d_in[1];
    const float* w_ih   = (const float*)d_in[2];
    const float* w_hh   = (const float*)d_in[3];
    const float* bias   = (const float*)d_in[4];
    const float* bias_n = (const float*)d_in[5];
    const float* out_w  = (const float*)d_in[6];
    const float* out_b  = (const float*)d_in[7];
    const float* init_h = (const float*)d_in[8];

    gru_seq_kernel<<<NCELLS / 64, 64, 0, stream>>>(
        precip, temp, w_ih, w_hh, bias, bias_n, out_w, out_b, init_h,
        (float*)d_out);
}

// Round 2
// 2404.920 us; speedup vs baseline: 10.0206x; 10.0206x over previous
//
#include <hip/hip_runtime.h>

#define T_STEPS 365
#define NCELLS  65536

typedef __attribute__((ext_vector_type(8))) short short8;   // 8 bf16 = 4 VGPRs
typedef __attribute__((ext_vector_type(4))) float f32x4;

static __device__ __forceinline__ short f2bf_rne(float x) {
    union { float f; unsigned u; } v; v.f = x;
    unsigned r = v.u + 0x7fffu + ((v.u >> 16) & 1u);   // round-nearest-even
    return (short)(r >> 16);
}
static __device__ __forceinline__ float bf2f(short b) {
    union { float f; unsigned u; } v; v.u = ((unsigned)(unsigned short)b) << 16;
    return v.f;
}
static __device__ __forceinline__ float fast_rcp(float x) { return __builtin_amdgcn_rcpf(x); }

// One wave = 16 cells for all 365 steps. h@W_hh^T on MFMA (W register-resident,
// split-h bf16 hi+lo for fp32-class accuracy). Elementwise in MFMA C-layout
// (lane: col c = unit group 16j+c, rows 4q+reg = cells). C->A layout transpose
// between steps via wave-private LDS (no barriers). Block=256 (4 indep waves).
__global__ __launch_bounds__(256, 2)
void gru_mfma_kernel(const float* __restrict__ precip,
                     const float* __restrict__ temp,
                     const float* __restrict__ w_ih,    // (192,2)
                     const float* __restrict__ w_hh,    // (192,64)
                     const float* __restrict__ bias,    // (192)
                     const float* __restrict__ bias_n,  // (64)
                     const float* __restrict__ out_w,   // (64)
                     const float* __restrict__ out_b,   // (1)
                     const float* __restrict__ init_h,  // (64)
                     float* __restrict__ out)
{
    __shared__ float hbuf[4][16][68];   // [wave][cell-local][unit], stride 68: float4-aligned, 2-way writes

    const int lane = threadIdx.x & 63;
    const int wid  = threadIdx.x >> 6;
    const int c    = lane & 15;         // A-row / D-col index
    const int q    = lane >> 4;         // quad
    const int base = (blockIdx.x * 4 + wid) * 16;   // first cell of this wave

    // ---- register-resident B fragments: B[k][g] = w_hh[g][k], tile jt = gates 16jt..16jt+15
    short8 Bf[12][2];
#pragma unroll
    for (int jt = 0; jt < 12; ++jt)
#pragma unroll
        for (int f = 0; f < 2; ++f) {
            const float* src = w_hh + ((16 * jt + c) * 64 + 32 * f + 8 * q);
#pragma unroll
            for (int e = 0; e < 8; ++e) Bf[jt][f][e] = f2bf_rne(src[e]);
        }

    // ---- per-lane constants for igates / biases / out_w (unit u = 16j + c)
    float wr0[4], wr1[4], wz0[4], wz1[4], wn0[4], wn1[4];
    float br[4], bz[4], bn_[4], bnn[4], ow[4];
#pragma unroll
    for (int j = 0; j < 4; ++j) {
        const int u = 16 * j + c;
        wr0[j] = w_ih[2 * u];       wr1[j] = w_ih[2 * u + 1];
        wz0[j] = w_ih[128 + 2 * u]; wz1[j] = w_ih[129 + 2 * u];
        wn0[j] = w_ih[256 + 2 * u]; wn1[j] = w_ih[257 + 2 * u];
        br[j]  = bias[u]; bz[j] = bias[64 + u]; bn_[j] = bias[128 + u];
        bnn[j] = bias_n[u]; ow[j] = out_w[u];
    }
    const float ob = out_b[0];

    // ---- h state in C-layout: hC[j][reg] = h[cell 4q+reg][unit 16j+c]
    float hC[4][4];
#pragma unroll
    for (int j = 0; j < 4; ++j) {
        const float iv = init_h[16 * j + c];
#pragma unroll
        for (int reg = 0; reg < 4; ++reg) hC[j][reg] = iv;
    }
    // prime LDS with A-layout h
#pragma unroll
    for (int j = 0; j < 4; ++j)
#pragma unroll
        for (int reg = 0; reg < 4; ++reg)
            hbuf[wid][4 * q + reg][16 * j + c] = hC[j][reg];

    const bool selb0 = (c & 1), selb1 = (c & 2);
    const bool do_store = (c < 4);

#pragma unroll 1
    for (int t = 0; t < T_STEPS; ++t) {
        const size_t tofs = (size_t)t * NCELLS + base;
        // x inputs for this wave's 4 cell-rows (lane-redundant across c, L1-cached)
        float pv[4], tv[4];
#pragma unroll
        for (int reg = 0; reg < 4; ++reg) {
            pv[reg] = precip[tofs + 4 * q + reg];
            tv[reg] = temp  [tofs + 4 * q + reg];
        }

        // ---- A-frags from LDS (lane c = cell-local row c), split hi/lo bf16
        const float* row = &hbuf[wid][c][0];
        f32x4 a0 = *(const f32x4*)(row + 8 * q);          // k = 8q..8q+3
        f32x4 a1 = *(const f32x4*)(row + 8 * q + 4);      // k = 8q+4..8q+7
        f32x4 a2 = *(const f32x4*)(row + 32 + 8 * q);     // k-frag 1
        f32x4 a3 = *(const f32x4*)(row + 32 + 8 * q + 4);
        short8 ah0, al0, ah1, al1;
#pragma unroll
        for (int e = 0; e < 4; ++e) {
            short h0 = f2bf_rne(a0[e]); ah0[e]     = h0; al0[e]     = f2bf_rne(a0[e] - bf2f(h0));
            short h1 = f2bf_rne(a1[e]); ah0[4 + e] = h1; al0[4 + e] = f2bf_rne(a1[e] - bf2f(h1));
            short h2 = f2bf_rne(a2[e]); ah1[e]     = h2; al1[e]     = f2bf_rne(a2[e] - bf2f(h2));
            short h3 = f2bf_rne(a3[e]); ah1[4 + e] = h3; al1[4 + e] = f2bf_rne(a3[e] - bf2f(h3));
        }

        // ---- hgates = [h_hi + h_lo] @ W^T : 48 MFMAs on the matrix pipe
        f32x4 acc[12];
#pragma unroll
        for (int jt = 0; jt < 12; ++jt) {
            f32x4 a = {0.f, 0.f, 0.f, 0.f};
            a = __builtin_amdgcn_mfma_f32_16x16x32_bf16(ah0, Bf[jt][0], a, 0, 0, 0);
            a = __builtin_amdgcn_mfma_f32_16x16x32_bf16(ah1, Bf[jt][1], a, 0, 0, 0);
            a = __builtin_amdgcn_mfma_f32_16x16x32_bf16(al0, Bf[jt][0], a, 0, 0, 0);
            a = __builtin_amdgcn_mfma_f32_16x16x32_bf16(al1, Bf[jt][1], a, 0, 0, 0);
            acc[jt] = a;
        }

        // ---- elementwise GRU update in C-layout (overlaps MFMA drain)
        float psum[4] = {0.f, 0.f, 0.f, 0.f};
#pragma unroll
        for (int j = 0; j < 4; ++j) {
#pragma unroll
            for (int reg = 0; reg < 4; ++reg) {
                const float hr = acc[j][reg];
                const float hz = acc[4 + j][reg];
                const float hn = acc[8 + j][reg];
                const float ir = fmaf(wr0[j], pv[reg], fmaf(wr1[j], tv[reg], br[j]));
                const float iz = fmaf(wz0[j], pv[reg], fmaf(wz1[j], tv[reg], bz[j]));
                const float in_= fmaf(wn0[j], pv[reg], fmaf(wn1[j], tv[reg], bn_[j]));
                const float r  = fast_rcp(1.f + __expf(-(ir + hr)));
                const float z  = fast_rcp(1.f + __expf(-(iz + hz)));
                const float a_ = fmaf(r, hn + bnn[j], in_);
                const float th = 1.f - 2.f * fast_rcp(1.f + __expf(a_ + a_)); // tanh
                const float hnew = fmaf(z, hC[j][reg] - th, th);
                hC[j][reg] = hnew;
                psum[reg] = fmaf(hnew, ow[j], psum[reg]);
            }
        }

        // ---- write h' back to LDS in A-layout order (transpose), no barrier needed
#pragma unroll
        for (int j = 0; j < 4; ++j)
#pragma unroll
            for (int reg = 0; reg < 4; ++reg)
                hbuf[wid][4 * q + reg][16 * j + c] = hC[j][reg];

        // ---- y = h' @ out_w^T + ob : butterfly over the 16 lanes of each quad
#pragma unroll
        for (int reg = 0; reg < 4; ++reg) {
            psum[reg] += __shfl_xor(psum[reg], 1);
            psum[reg] += __shfl_xor(psum[reg], 2);
            psum[reg] += __shfl_xor(psum[reg], 4);
            psum[reg] += __shfl_xor(psum[reg], 8);
        }
        float ya = selb0 ? psum[1] : psum[0];
        float yb = selb0 ? psum[3] : psum[2];
        float yv = selb1 ? yb : ya;
        if (do_store) out[tofs + 4 * q + c] = yv + ob;   // 16 contiguous floats per wave
    }

    // ---- final_h: out[T*N + cell*64 + u]
    const size_t fofs = (size_t)T_STEPS * NCELLS + (size_t)base * 64;
#pragma unroll
    for (int j = 0; j < 4; ++j)
#pragma unroll
        for (int reg = 0; reg < 4; ++reg)
            out[fofs + (size_t)(4 * q + reg) * 64 + 16 * j + c] = hC[j][reg];
}

extern "C" void kernel_launch(void* const* d_in, const int* in_sizes, int n_in,
                              void* d_out, int out_size, void* d_ws, size_t ws_size,
                              hipStream_t stream) {
    const float* precip = (const float*)d_in[0];
    const float* temp   = (const float*)d_in[1];
    const float* w_ih   = (const float*)d_in[2];
    const float* w_hh   = (const float*)d_in[3];
    const float* bias   = (const float*)d_in[4];
    const float* bias_n = (const float*)d_in[5];
    const float* out_w  = (const float*)d_in[6];
    const float* out_b  = (const float*)d_in[7];
    const float* init_h = (const float*)d_in[8];

    gru_mfma_kernel<<<NCELLS / 64, 256, 0, stream>>>(
        precip, temp, w_ih, w_hh, bias, bias_n, out_w, out_b, init_h,
        (float*)d_out);
}